// Round 1
// baseline (1060.444 us; speedup 1.0000x reference)
//
#include <hip/hip_runtime.h>
#include <cstdint>
#include <cstddef>

#define TT 512
#define BB 128
#define EE 128
#define SS 1024

// ---------- bf16 helpers ----------
__device__ __forceinline__ float bf_lo(unsigned int w) {
    unsigned int b = w << 16; float f; __builtin_memcpy(&f, &b, 4); return f;
}
__device__ __forceinline__ float bf_hi(unsigned int w) {
    unsigned int b = w & 0xFFFF0000u; float f; __builtin_memcpy(&f, &b, 4); return f;
}
__device__ __forceinline__ unsigned int f2bf(float f) {   // RNE
    unsigned int b; __builtin_memcpy(&b, &f, 4);
    b += 0x7FFFu + ((b >> 16) & 1u);
    return b >> 16;
}
__device__ __forceinline__ unsigned int pack2(float x, float y) {
    return f2bf(x) | (f2bf(y) << 16);
}
__device__ __forceinline__ float bf2f(unsigned short u) {
    unsigned int b = ((unsigned int)u) << 16; float f; __builtin_memcpy(&f, &b, 4); return f;
}

// ============================================================
// Phase A: per-batch sequential strengths evolution.
// 128 blocks (one per b) x 64 threads (one wave). Strengths live in
// registers: lane holds slots [16*lane, 16*lane+16). Writes pre-pop
// strengths (bf16) for valid slots s < 2t+2 each step.
// ============================================================
__global__ __launch_bounds__(64) void phaseA(
    const float* __restrict__ d1, const float* __restrict__ d2,
    const float* __restrict__ u, unsigned short* __restrict__ P)
{
    const int b = blockIdx.x;
    const int lane = threadIdx.x;
    const int s_base = lane * 16;

    float a[16];
#pragma unroll
    for (int j = 0; j < 16; ++j) a[j] = 0.f;

    for (int t = 0; t < TT; ++t) {
        const float d1t = d1[t * BB + b];
        const float d2t = d2[t * BB + b];
        const float ut  = u [t * BB + b];

        // push at slots 2t, 2t+1 (predicated per unrolled j)
        const int p0 = 2 * t - s_base;
#pragma unroll
        for (int j = 0; j < 16; ++j) {
            if (j == p0)     a[j] = d1t;
            if (j == p0 + 1) a[j] = d2t;
        }

        // local sum + wave-level inclusive suffix scan (higher lane = higher slot)
        float ls = 0.f;
#pragma unroll
        for (int j = 0; j < 16; ++j) ls += a[j];
        float v = ls;
#pragma unroll
        for (int off = 1; off < 64; off <<= 1) {
            float o = __shfl_down(v, off);
            if (lane + off < 64) v += o;
        }
        const float excl = v - ls;   // sum over slots strictly above my chunk

        float used[16];
        used[15] = excl;
#pragma unroll
        for (int j = 14; j >= 0; --j) used[j] = used[j + 1] + a[j + 1];

        // store pre-pop strengths (bf16) for s < nv
        const int nv = 2 * t + 2;
        unsigned short* row = P + ((size_t)b * TT + t) * SS;
        if (s_base + 16 <= nv) {
            uint4 w0, w1;
            w0.x = pack2(a[0],  a[1]);  w0.y = pack2(a[2],  a[3]);
            w0.z = pack2(a[4],  a[5]);  w0.w = pack2(a[6],  a[7]);
            w1.x = pack2(a[8],  a[9]);  w1.y = pack2(a[10], a[11]);
            w1.z = pack2(a[12], a[13]); w1.w = pack2(a[14], a[15]);
            ((uint4*)(row + s_base))[0] = w0;
            ((uint4*)(row + s_base))[1] = w1;
        } else if (s_base < nv) {
#pragma unroll
            for (int j = 0; j < 16; ++j)
                if (s_base + j < nv) row[s_base + j] = (unsigned short)f2bf(a[j]);
        }

        // pop (uses pre-pop a and used)
#pragma unroll
        for (int j = 0; j < 16; ++j) {
            float g = ut - used[j];
            a[j] -= fminf(a[j], fmaxf(0.f, g));
        }
    }
}

// ============================================================
// Phase B: m[t,s] = max_b (u[t,b] - used[t,b,s]).
// 512 blocks (one per t) x 64 threads. Recomputes used from bf16 rows.
// ============================================================
__global__ __launch_bounds__(64) void phaseB(
    const unsigned short* __restrict__ P, const float* __restrict__ u,
    float* __restrict__ m)
{
    const int t = blockIdx.x;
    const int lane = threadIdx.x;
    const int nv = 2 * t + 2;
    const int s_base = lane * 16;

    float mm[16];
#pragma unroll
    for (int j = 0; j < 16; ++j) mm[j] = -3.4e38f;

    for (int b = 0; b < BB; ++b) {
        const unsigned short* row = P + ((size_t)b * TT + t) * SS + s_base;
        float a[16];
        if (s_base + 16 <= nv) {
            uint4 pA = ((const uint4*)row)[0];
            uint4 pB = ((const uint4*)row)[1];
            a[0]=bf_lo(pA.x); a[1]=bf_hi(pA.x); a[2]=bf_lo(pA.y); a[3]=bf_hi(pA.y);
            a[4]=bf_lo(pA.z); a[5]=bf_hi(pA.z); a[6]=bf_lo(pA.w); a[7]=bf_hi(pA.w);
            a[8]=bf_lo(pB.x); a[9]=bf_hi(pB.x); a[10]=bf_lo(pB.y); a[11]=bf_hi(pB.y);
            a[12]=bf_lo(pB.z); a[13]=bf_hi(pB.z); a[14]=bf_lo(pB.w); a[15]=bf_hi(pB.w);
        } else if (s_base < nv) {
#pragma unroll
            for (int j = 0; j < 16; ++j)
                a[j] = (s_base + j < nv) ? bf2f(row[j]) : 0.f;
        } else {
#pragma unroll
            for (int j = 0; j < 16; ++j) a[j] = 0.f;
        }

        float ls = 0.f;
#pragma unroll
        for (int j = 0; j < 16; ++j) ls += a[j];
        float v = ls;
#pragma unroll
        for (int off = 1; off < 64; off <<= 1) {
            float o = __shfl_down(v, off);
            if (lane + off < 64) v += o;
        }
        const float excl = v - ls;

        float used[16];
        used[15] = excl;
#pragma unroll
        for (int j = 14; j >= 0; --j) used[j] = used[j + 1] + a[j + 1];

        const float ub = u[t * BB + b];
#pragma unroll
        for (int j = 0; j < 16; ++j) mm[j] = fmaxf(mm[j], ub - used[j]);
    }

    float* mrow = m + (size_t)t * SS + s_base;
    if (s_base + 16 <= nv) {
        ((float4*)mrow)[0] = make_float4(mm[0],  mm[1],  mm[2],  mm[3]);
        ((float4*)mrow)[1] = make_float4(mm[4],  mm[5],  mm[6],  mm[7]);
        ((float4*)mrow)[2] = make_float4(mm[8],  mm[9],  mm[10], mm[11]);
        ((float4*)mrow)[3] = make_float4(mm[12], mm[13], mm[14], mm[15]);
    } else if (s_base < nv) {
#pragma unroll
        for (int j = 0; j < 16; ++j)
            if (s_base + j < nv) mrow[j] = mm[j];
    }
}

// ============================================================
// Phase C: out[t,b,e] = sum_{s<2t+2} min(P[t,b,s], m[t,s]) * V[b,s,e]
// where V[b,2i,e]=v1[i,b,e], V[b,2i+1,e]=v2[i,b,e].
// Grid: 1024 blocks = b (128) x t-tile (8, heavy tiles first) x 256 thr.
// Tile: 64 t-rows x 128 e-cols, K-chunks of 64 slots. Triangular skip.
// ============================================================
__global__ __launch_bounds__(256) void phaseC(
    const unsigned short* __restrict__ P, const float* __restrict__ m,
    const float* __restrict__ v1, const float* __restrict__ v2,
    float* __restrict__ out)
{
    const int b  = blockIdx.x & (BB - 1);
    const int tt = 7 - (blockIdx.x >> 7);   // heavy tiles launch first
    const int t0 = tt * 64;
    const int tid = threadIdx.x;

    __shared__ float Ws[64][65];    // [t][s] padded (+1) to break conflicts
    __shared__ float Vs[64][132];   // [s][e] padded (+4)

    float acc[4][8];
#pragma unroll
    for (int i = 0; i < 4; ++i)
#pragma unroll
        for (int j = 0; j < 8; ++j) acc[i][j] = 0.f;

    const int r = (tid >> 4) * 4;       // my 4 t-rows
    const int c = (tid & 15) * 8;       // my 8 e-cols
    const int wi = tid >> 2;            // staging row (0..63)
    const int wj = (tid & 3) * 16;      // W staging col base
    const int ve = (tid & 3) * 32;      // V staging col base

    const int nchunks = 2 * tt + 2;     // covers s < 2*t0+128

    for (int ch = 0; ch < nchunks; ++ch) {
        const int sb = ch * 64;

        // ---- stage W tile: min(P, m), masked to s < 2t+2 ----
        {
            const int t_row = t0 + wi;
            const int nv = 2 * t_row + 2;
            const unsigned short* prow = P + ((size_t)b * TT + t_row) * SS + sb + wj;
            const float* mrow = m + (size_t)t_row * SS + sb + wj;
            uint4 pA = ((const uint4*)prow)[0];
            uint4 pB = ((const uint4*)prow)[1];
            unsigned int pu[8] = {pA.x, pA.y, pA.z, pA.w, pB.x, pB.y, pB.z, pB.w};
            float mfv[16];
#pragma unroll
            for (int q4 = 0; q4 < 4; ++q4)
                *(float4*)&mfv[q4 * 4] = ((const float4*)mrow)[q4];
#pragma unroll
            for (int q = 0; q < 16; ++q) {
                float pf = (q & 1) ? bf_hi(pu[q >> 1]) : bf_lo(pu[q >> 1]);
                int s = sb + wj + q;
                Ws[wi][wj + q] = (s < nv) ? fminf(pf, mfv[q]) : 0.f;
            }
        }

        // ---- stage V tile: rows s = sb+wi from v1/v2 ----
        {
            const int s = sb + wi;
            const int isrc = s >> 1;
            const float* src = ((s & 1) ? v2 : v1)
                             + ((size_t)isrc * BB + b) * EE + ve;
            float4* dst = (float4*)&Vs[wi][ve];
#pragma unroll
            for (int q = 0; q < 8; ++q) dst[q] = ((const float4*)src)[q];
        }

        __syncthreads();

        // ---- compute: 64 k-steps, 4x8 per-thread outer product ----
        for (int k = 0; k < 64; ++k) {
            float wv[4];
#pragma unroll
            for (int i = 0; i < 4; ++i) wv[i] = Ws[r + i][k];
            float vv[8];
            *(float4*)&vv[0] = *(const float4*)&Vs[k][c];
            *(float4*)&vv[4] = *(const float4*)&Vs[k][c + 4];
#pragma unroll
            for (int i = 0; i < 4; ++i)
#pragma unroll
                for (int j = 0; j < 8; ++j)
                    acc[i][j] = fmaf(wv[i], vv[j], acc[i][j]);
        }

        __syncthreads();
    }

    // ---- epilogue ----
#pragma unroll
    for (int i = 0; i < 4; ++i) {
        float* orow = out + ((size_t)(t0 + r + i) * BB + b) * EE + c;
        *(float4*)orow       = make_float4(acc[i][0], acc[i][1], acc[i][2], acc[i][3]);
        *(float4*)(orow + 4) = make_float4(acc[i][4], acc[i][5], acc[i][6], acc[i][7]);
    }
}

// ============================================================
extern "C" void kernel_launch(void* const* d_in, const int* in_sizes, int n_in,
                              void* d_out, int out_size, void* d_ws, size_t ws_size,
                              hipStream_t stream) {
    const float* v1 = (const float*)d_in[0];
    const float* v2 = (const float*)d_in[1];
    const float* d1 = (const float*)d_in[2];
    const float* d2 = (const float*)d_in[3];
    const float* u  = (const float*)d_in[4];
    float* out = (float*)d_out;

    unsigned short* P = (unsigned short*)d_ws;                       // [B][T][S] bf16, 134.2 MB
    float* m = (float*)((char*)d_ws + (size_t)BB * TT * SS * 2);     // [T][S] fp32, 2 MB

    phaseA<<<dim3(BB), dim3(64), 0, stream>>>(d1, d2, u, P);
    phaseB<<<dim3(TT), dim3(64), 0, stream>>>(P, u, m);
    phaseC<<<dim3(BB * 8), dim3(256), 0, stream>>>(P, m, v1, v2, out);
}

// Round 2
// 443.867 us; speedup vs baseline: 2.3891x; 2.3891x over previous
//
#include <hip/hip_runtime.h>
#include <cstdint>
#include <cstddef>

#define TT 512
#define BB 128
#define EE 128
#define SS 1024

// ---------- fp16 helpers ----------
__device__ __forceinline__ unsigned int pkh(float x, float y) {
    _Float16 hx = (_Float16)x, hy = (_Float16)y;
    unsigned short bx, by;
    __builtin_memcpy(&bx, &hx, 2); __builtin_memcpy(&by, &hy, 2);
    return (unsigned int)bx | ((unsigned int)by << 16);
}
__device__ __forceinline__ unsigned short f2h(float x) {
    _Float16 h = (_Float16)x; unsigned short b; __builtin_memcpy(&b, &h, 2); return b;
}
__device__ __forceinline__ float h2f(unsigned short u) {
    _Float16 h; __builtin_memcpy(&h, &u, 2); return (float)h;
}
__device__ __forceinline__ float h_lo(unsigned int w) { return h2f((unsigned short)(w & 0xFFFFu)); }
__device__ __forceinline__ float h_hi(unsigned int w) { return h2f((unsigned short)(w >> 16)); }

// ============================================================
// Phase A — suffix-sum-space recurrence, fully pointwise.
// c[j] = sum_{k>=j} strengths[k].
//   push: c[j] += d1+d2 (j<=2t);  c[2t+1] = d2
//   a[j] = c[j] - c[j+1]   (pre-pop strengths, stored fp16)
//   pop:  c[j] = max(0, c[j] - u)
// 128 blocks (one per b) x 128 threads (2 waves). Lane owns 8 slots
// [8*tid, 8*tid+8) plus a DUPLICATE of slot 8*tid+8 (c[8]) maintained
// by the same pointwise updates -> no cross-lane traffic at all.
// ============================================================
__global__ __launch_bounds__(128) void phaseA(
    const float* __restrict__ d1, const float* __restrict__ d2,
    const float* __restrict__ u, unsigned short* __restrict__ P)
{
    const int b = blockIdx.x;
    const int tid = threadIdx.x;

    __shared__ float sd1[TT], sd2[TT], su[TT];
    for (int i = tid; i < TT; i += 128) {
        sd1[i] = d1[i * BB + b];
        sd2[i] = d2[i * BB + b];
        su[i]  = u [i * BB + b];
    }
    __syncthreads();

    const int base = tid * 8;          // slots [base, base+8); c[8] dups slot base+8
    float c[9];
#pragma unroll
    for (int j = 0; j < 9; ++j) c[j] = 0.f;

    unsigned short* Pb = P + (size_t)b * TT * SS;

    for (int t = 0; t < TT; ++t) {
        const float d1t = sd1[t], d2t = sd2[t], ut = su[t];
        const float dd = d1t + d2t;
        const int top = 2 * t;

        // push (pointwise)
#pragma unroll
        for (int j = 0; j < 9; ++j) {
            const int s = base + j;
            if (s <= top)     c[j] += dd;
            if (s == top + 1) c[j] = d2t;
        }

        // store pre-pop strengths a = adjacent diff of c
        const int nv = top + 2;
        if (base < nv) {
            float a[8];
#pragma unroll
            for (int j = 0; j < 8; ++j) a[j] = c[j] - c[j + 1];
            unsigned short* row = Pb + (size_t)t * SS;
            if (base + 8 <= nv) {
                uint4 st;
                st.x = pkh(a[0], a[1]); st.y = pkh(a[2], a[3]);
                st.z = pkh(a[4], a[5]); st.w = pkh(a[6], a[7]);
                *(uint4*)(row + base) = st;
            } else {
                const int n = nv - base;   // 2, 4, or 6
#pragma unroll
                for (int j = 0; j < 8; ++j)
                    if (j < n) row[base + j] = f2h(a[j]);
            }
        }

        // pop (pointwise): c = max(0, c - u)
#pragma unroll
        for (int j = 0; j < 9; ++j) c[j] = fmaxf(0.f, c[j] - ut);
    }
}

// ============================================================
// Phase B: m[t,s] = max_b (u[t,b] - used[t,b,s]).
// 512 blocks (one per t) x 256 threads (4 waves); each wave handles
// b = w, w+4, ..., scanning its row; LDS max-reduce across waves.
// ============================================================
__global__ __launch_bounds__(256) void phaseB(
    const unsigned short* __restrict__ P, const float* __restrict__ u,
    float* __restrict__ m)
{
    const int t = blockIdx.x;
    const int tid = threadIdx.x;
    const int lane = tid & 63, w = tid >> 6;
    const int nv = 2 * t + 2;
    const int s_base = lane * 16;

    __shared__ float red[4][64][17];   // +1 pad breaks bank conflicts

    float mm[16];
#pragma unroll
    for (int j = 0; j < 16; ++j) mm[j] = -3.4e38f;

    for (int b = w; b < BB; b += 4) {
        const unsigned short* row = P + ((size_t)b * TT + t) * SS + s_base;
        float a[16];
        if (s_base + 16 <= nv) {
            uint4 pA = ((const uint4*)row)[0];
            uint4 pB = ((const uint4*)row)[1];
            a[0]=h_lo(pA.x);  a[1]=h_hi(pA.x);  a[2]=h_lo(pA.y);  a[3]=h_hi(pA.y);
            a[4]=h_lo(pA.z);  a[5]=h_hi(pA.z);  a[6]=h_lo(pA.w);  a[7]=h_hi(pA.w);
            a[8]=h_lo(pB.x);  a[9]=h_hi(pB.x);  a[10]=h_lo(pB.y); a[11]=h_hi(pB.y);
            a[12]=h_lo(pB.z); a[13]=h_hi(pB.z); a[14]=h_lo(pB.w); a[15]=h_hi(pB.w);
        } else if (s_base < nv) {
#pragma unroll
            for (int j = 0; j < 16; ++j)
                a[j] = (s_base + j < nv) ? h2f(row[j]) : 0.f;
        } else {
#pragma unroll
            for (int j = 0; j < 16; ++j) a[j] = 0.f;
        }

        float ls = 0.f;
#pragma unroll
        for (int j = 0; j < 16; ++j) ls += a[j];
        float v = ls;
#pragma unroll
        for (int off = 1; off < 64; off <<= 1) {
            float o = __shfl_down(v, off);
            if (lane + off < 64) v += o;
        }
        const float excl = v - ls;     // strength strictly above my chunk

        float used[16];
        used[15] = excl;
#pragma unroll
        for (int j = 14; j >= 0; --j) used[j] = used[j + 1] + a[j + 1];

        const float ub = u[t * BB + b];
#pragma unroll
        for (int j = 0; j < 16; ++j) mm[j] = fmaxf(mm[j], ub - used[j]);
    }

#pragma unroll
    for (int j = 0; j < 16; ++j) red[w][lane][j] = mm[j];
    __syncthreads();

    if (tid < 64) {
#pragma unroll
        for (int j = 0; j < 16; ++j)
            mm[j] = fmaxf(fmaxf(red[0][tid][j], red[1][tid][j]),
                          fmaxf(red[2][tid][j], red[3][tid][j]));
        float* mrow = m + (size_t)t * SS + s_base;
        if (s_base + 16 <= nv) {
            ((float4*)mrow)[0] = make_float4(mm[0],  mm[1],  mm[2],  mm[3]);
            ((float4*)mrow)[1] = make_float4(mm[4],  mm[5],  mm[6],  mm[7]);
            ((float4*)mrow)[2] = make_float4(mm[8],  mm[9],  mm[10], mm[11]);
            ((float4*)mrow)[3] = make_float4(mm[12], mm[13], mm[14], mm[15]);
        } else if (s_base < nv) {
#pragma unroll
            for (int j = 0; j < 16; ++j)
                if (s_base + j < nv) mrow[j] = mm[j];
        }
    }
}

// ============================================================
// Phase C: out[t,b,e] = sum_{s<2t+2} min(P[t,b,s], m[t,s]) * V[b,s,e]
// V[b,2i,e]=v1[i,b,e], V[b,2i+1,e]=v2[i,b,e].
// Grid: 1024 blocks = b (128) x t-tile (8, heavy first) x 256 thr.
// ============================================================
__global__ __launch_bounds__(256) void phaseC(
    const unsigned short* __restrict__ P, const float* __restrict__ m,
    const float* __restrict__ v1, const float* __restrict__ v2,
    float* __restrict__ out)
{
    const int b  = blockIdx.x & (BB - 1);
    const int tt = 7 - (blockIdx.x >> 7);
    const int t0 = tt * 64;
    const int tid = threadIdx.x;

    __shared__ float Ws[64][65];
    __shared__ float Vs[64][132];

    float acc[4][8];
#pragma unroll
    for (int i = 0; i < 4; ++i)
#pragma unroll
        for (int j = 0; j < 8; ++j) acc[i][j] = 0.f;

    const int r = (tid >> 4) * 4;
    const int c = (tid & 15) * 8;
    const int wi = tid >> 2;
    const int wj = (tid & 3) * 16;
    const int ve = (tid & 3) * 32;

    const int nchunks = 2 * tt + 2;

    for (int ch = 0; ch < nchunks; ++ch) {
        const int sb = ch * 64;

        // stage W tile: min(P, m), masked to s < 2t+2
        {
            const int t_row = t0 + wi;
            const int nv = 2 * t_row + 2;
            const unsigned short* prow = P + ((size_t)b * TT + t_row) * SS + sb + wj;
            const float* mrow = m + (size_t)t_row * SS + sb + wj;
            uint4 pA = ((const uint4*)prow)[0];
            uint4 pB = ((const uint4*)prow)[1];
            unsigned int pu[8] = {pA.x, pA.y, pA.z, pA.w, pB.x, pB.y, pB.z, pB.w};
            float mfv[16];
#pragma unroll
            for (int q4 = 0; q4 < 4; ++q4)
                *(float4*)&mfv[q4 * 4] = ((const float4*)mrow)[q4];
#pragma unroll
            for (int q = 0; q < 16; ++q) {
                float pf = (q & 1) ? h_hi(pu[q >> 1]) : h_lo(pu[q >> 1]);
                int s = sb + wj + q;
                Ws[wi][wj + q] = (s < nv) ? fminf(pf, mfv[q]) : 0.f;
            }
        }

        // stage V tile
        {
            const int s = sb + wi;
            const int isrc = s >> 1;
            const float* src = ((s & 1) ? v2 : v1)
                             + ((size_t)isrc * BB + b) * EE + ve;
            float4* dst = (float4*)&Vs[wi][ve];
#pragma unroll
            for (int q = 0; q < 8; ++q) dst[q] = ((const float4*)src)[q];
        }

        __syncthreads();

        for (int k = 0; k < 64; ++k) {
            float wv[4];
#pragma unroll
            for (int i = 0; i < 4; ++i) wv[i] = Ws[r + i][k];
            float vv[8];
            *(float4*)&vv[0] = *(const float4*)&Vs[k][c];
            *(float4*)&vv[4] = *(const float4*)&Vs[k][c + 4];
#pragma unroll
            for (int i = 0; i < 4; ++i)
#pragma unroll
                for (int j = 0; j < 8; ++j)
                    acc[i][j] = fmaf(wv[i], vv[j], acc[i][j]);
        }

        __syncthreads();
    }

#pragma unroll
    for (int i = 0; i < 4; ++i) {
        float* orow = out + ((size_t)(t0 + r + i) * BB + b) * EE + c;
        *(float4*)orow       = make_float4(acc[i][0], acc[i][1], acc[i][2], acc[i][3]);
        *(float4*)(orow + 4) = make_float4(acc[i][4], acc[i][5], acc[i][6], acc[i][7]);
    }
}

// ============================================================
extern "C" void kernel_launch(void* const* d_in, const int* in_sizes, int n_in,
                              void* d_out, int out_size, void* d_ws, size_t ws_size,
                              hipStream_t stream) {
    const float* v1 = (const float*)d_in[0];
    const float* v2 = (const float*)d_in[1];
    const float* d1 = (const float*)d_in[2];
    const float* d2 = (const float*)d_in[3];
    const float* u  = (const float*)d_in[4];
    float* out = (float*)d_out;

    unsigned short* P = (unsigned short*)d_ws;                       // [B][T][S] fp16, 134.2 MB
    float* m = (float*)((char*)d_ws + (size_t)BB * TT * SS * 2);     // [T][S] fp32, 2 MB

    phaseA<<<dim3(BB), dim3(128), 0, stream>>>(d1, d2, u, P);
    phaseB<<<dim3(TT), dim3(256), 0, stream>>>(P, u, m);
    phaseC<<<dim3(BB * 8), dim3(256), 0, stream>>>(P, m, v1, v2, out);
}

// Round 3
// 366.591 us; speedup vs baseline: 2.8927x; 1.2108x over previous
//
#include <hip/hip_runtime.h>
#include <cstdint>
#include <cstddef>

#define TT 512
#define BB 128
#define EE 128
#define SS 1024

// ---------- fp16 helpers ----------
__device__ __forceinline__ unsigned int pkh(float x, float y) {
    _Float16 hx = (_Float16)x, hy = (_Float16)y;
    unsigned short bx, by;
    __builtin_memcpy(&bx, &hx, 2); __builtin_memcpy(&by, &hy, 2);
    return (unsigned int)bx | ((unsigned int)by << 16);
}
__device__ __forceinline__ float h2f(unsigned short u) {
    _Float16 h; __builtin_memcpy(&h, &u, 2); return (float)h;
}
__device__ __forceinline__ float h_lo(unsigned int w) { return h2f((unsigned short)(w & 0xFFFFu)); }
__device__ __forceinline__ float h_hi(unsigned int w) { return h2f((unsigned short)(w >> 16)); }

#define NEG_INF (-1e30f)

// ============================================================
// prefixF: per-b prefix sums. F[b][t] = sum_{k<=t}(u-d1-d2),
// Bv[b][t] = F[t-1] - d1[t], d2T[b][t] = d2[t,b], FT[t][b] = F[b][t].
// 128 blocks x 64 threads (1 wave), lane owns 8 consecutive t.
// ============================================================
__global__ __launch_bounds__(64) void prefixF(
    const float* __restrict__ d1, const float* __restrict__ d2,
    const float* __restrict__ u,
    float* __restrict__ F, float* __restrict__ Bv,
    float* __restrict__ d2T, float* __restrict__ FT)
{
    const int b = blockIdx.x;
    const int lane = threadIdx.x;
    const int t0 = lane * 8;

    float l1[8], l2[8], g[8];
#pragma unroll
    for (int j = 0; j < 8; ++j) {
        const int t = t0 + j;
        l1[j] = d1[t * BB + b];
        l2[j] = d2[t * BB + b];
        g[j] = u[t * BB + b] - l1[j] - l2[j];
    }
    float p[8], s = 0.f;
#pragma unroll
    for (int j = 0; j < 8; ++j) { s += g[j]; p[j] = s; }

    float v = s;
#pragma unroll
    for (int off = 1; off < 64; off <<= 1) {
        float o = __shfl_up(v, off);
        if (lane >= off) v += o;
    }
    const float excl = v - s;     // F_{t0-1} (0 for lane 0)

    float Fv[8];
#pragma unroll
    for (int j = 0; j < 8; ++j) Fv[j] = excl + p[j];

#pragma unroll
    for (int j = 0; j < 8; ++j) {
        const int t = t0 + j;
        const float Fm1 = (j > 0) ? Fv[j - 1] : excl;   // F_{t-1}; lane0,j0 -> 0
        F [b * TT + t] = Fv[j];
        Bv[b * TT + t] = Fm1 - l1[j];
        d2T[b * TT + t] = l2[j];
        FT[t * BB + b] = Fv[j];
    }
}

// ============================================================
// genP: fully parallel P generation from the closed form.
// Grid 1024 = b(128) x t-tile(8 of 64 rows). 256 threads; thread owns
// i0=2*tid, i1=2*tid+1 (slots 4*tid..4*tid+3), loops 64 rows with
// incrementally-maintained R_i(t). Seeded by log suffix-max scan.
// ============================================================
__global__ __launch_bounds__(256) void genP(
    const float* __restrict__ F, const float* __restrict__ Bvg,
    const float* __restrict__ d2T, unsigned short* __restrict__ P)
{
    const int b = blockIdx.x & (BB - 1);
    const int tile = blockIdx.x >> 7;
    const int t0 = tile * 64;
    const int lim = t0 + 64;
    const int tid = threadIdx.x;

    __shared__ float Fs[512];
    __shared__ float SM[512];
    __shared__ float d2s[64];

    for (int k = tid; k < lim; k += 256) Fs[k] = F[b * TT + k];
    if (tid < 64) d2s[tid] = d2T[b * TT + t0 + tid];
    __syncthreads();

    // SM[k] = max F over [k, t0-1]  (NEG_INF for k >= t0)
    const int k1 = tid, k2 = tid + 256;
    SM[k1] = (k1 < t0) ? Fs[k1] : NEG_INF;
    SM[k2] = (k2 < t0) ? Fs[k2] : NEG_INF;
    __syncthreads();
    for (int off = 1; off < t0; off <<= 1) {
        float a = SM[k1]; if (k1 + off < 512) a = fmaxf(a, SM[k1 + off]);
        float c = SM[k2]; if (k2 + off < 512) c = fmaxf(c, SM[k2 + off]);
        __syncthreads();
        SM[k1] = a; SM[k2] = c;
        __syncthreads();
    }

    const int i0 = 2 * tid, i1 = 2 * tid + 1;
    float R0 = SM[i0];
    float R1 = SM[i1];
    const float A0 = (i0 > 0) ? Fs[i0 - 1] : 0.f;   // F_{i0-1}
    const float A1 = Fs[i0];                        // F_{i1-1}
    const float B0 = Bvg[b * TT + i0];
    const float B1 = Bvg[b * TT + i1];

    unsigned short* Pbase = P + (size_t)b * TT * SS + 4 * tid;

    for (int row = 0; row < 64; ++row) {
        const int t = t0 + row;
        if (i0 > t) continue;
        const float Ft1 = (t > 0) ? Fs[t - 1] : 0.f;
        if (t > i0) R0 = fmaxf(R0, Ft1);
        if (t > i1) R1 = fmaxf(R1, Ft1);

        const float a0 = fmaxf(A0, R0) - fmaxf(B0, R0);
        const float a1 = (i0 == t) ? d2s[row] : fmaxf(B0 - R0, 0.f);
        if (i1 <= t) {
            const float a2 = fmaxf(A1, R1) - fmaxf(B1, R1);
            const float a3 = (i1 == t) ? d2s[row] : fmaxf(B1 - R1, 0.f);
            uint2 st; st.x = pkh(a0, a1); st.y = pkh(a2, a3);
            *(uint2*)(Pbase + (size_t)t * SS) = st;
        } else {
            *(unsigned int*)(Pbase + (size_t)t * SS) = pkh(a0, a1);
        }
    }
}

// ============================================================
// calcM: m[t,s] = max_b(u - used) via closed form; no P read.
// 512 blocks (one per t) x 256 threads. Threads 0..127 sweep i
// downward for their b (maintaining R); chunked (32 i = 64 s) with
// LDS staging + cross-b max reduction by all 256 threads.
// ============================================================
__global__ __launch_bounds__(256) void calcM(
    const float* __restrict__ F, const float* __restrict__ Bvg,
    const float* __restrict__ FT, const float* __restrict__ u,
    float* __restrict__ m)
{
    const int t = blockIdx.x;
    const int tid = threadIdx.x;

    __shared__ float Fs[BB][33];
    __shared__ float Bs[BB][33];
    __shared__ float cand[BB][65];
    __shared__ float red[4][64];
    __shared__ float us[BB];
    __shared__ float Ftb[BB];
    __shared__ float Rc[BB];

    if (tid < BB) {
        us[tid]  = u[t * BB + tid];
        Ftb[tid] = FT[t * BB + tid];
        Rc[tid]  = NEG_INF;
    }

    const int nck = (t >> 5) + 1;
    for (int ck = nck - 1; ck >= 0; --ck) {
        const int ib = ck * 32;
        __syncthreads();
        for (int q = tid; q < BB * 32; q += 256) {
            const int bb = q >> 5, j = q & 31;
            Fs[bb][j] = F  [bb * TT + ib + j];
            Bs[bb][j] = Bvg[bb * TT + ib + j];
        }
        __syncthreads();

        if (tid < BB) {
            const int b = tid;
            float R = Rc[b];
            const float Ft = Ftb[b];
            const int itop = min(t, ib + 31);
            for (int i = itop; i >= ib; --i) {
                const int j = i - ib;
                if (i < t) R = fmaxf(R, Fs[b][j]);
                cand[b][2 * j]     = Ft - fmaxf(Bs[b][j], R);
                cand[b][2 * j + 1] = (i == t) ? us[b] : (Ft - R);
            }
            Rc[b] = R;
        }
        __syncthreads();

        // cross-b max for 64 s-columns
        {
            const int s = tid & 63, g = tid >> 6;
            float mx = NEG_INF;
            const int b0 = g * 32;
#pragma unroll 8
            for (int bb = b0; bb < b0 + 32; ++bb) mx = fmaxf(mx, cand[bb][s]);
            red[g][s] = mx;
            __syncthreads();
            if (tid < 64) {
                const float r = fmaxf(fmaxf(red[0][tid], red[1][tid]),
                                      fmaxf(red[2][tid], red[3][tid]));
                const int s_glob = 64 * ck + tid;
                if (s_glob < 2 * t + 2) m[(size_t)t * SS + s_glob] = r;
            }
        }
    }
}

// ============================================================
// Phase C (unchanged): out[t,b,e] = sum_{s<2t+2} min(P,m) * V[b,s,e]
// ============================================================
__global__ __launch_bounds__(256) void phaseC(
    const unsigned short* __restrict__ P, const float* __restrict__ m,
    const float* __restrict__ v1, const float* __restrict__ v2,
    float* __restrict__ out)
{
    const int b  = blockIdx.x & (BB - 1);
    const int tt = 7 - (blockIdx.x >> 7);
    const int t0 = tt * 64;
    const int tid = threadIdx.x;

    __shared__ float Ws[64][65];
    __shared__ float Vs[64][132];

    float acc[4][8];
#pragma unroll
    for (int i = 0; i < 4; ++i)
#pragma unroll
        for (int j = 0; j < 8; ++j) acc[i][j] = 0.f;

    const int r = (tid >> 4) * 4;
    const int c = (tid & 15) * 8;
    const int wi = tid >> 2;
    const int wj = (tid & 3) * 16;
    const int ve = (tid & 3) * 32;

    const int nchunks = 2 * tt + 2;

    for (int ch = 0; ch < nchunks; ++ch) {
        const int sb = ch * 64;

        {
            const int t_row = t0 + wi;
            const int nv = 2 * t_row + 2;
            const unsigned short* prow = P + ((size_t)b * TT + t_row) * SS + sb + wj;
            const float* mrow = m + (size_t)t_row * SS + sb + wj;
            uint4 pA = ((const uint4*)prow)[0];
            uint4 pB = ((const uint4*)prow)[1];
            unsigned int pu[8] = {pA.x, pA.y, pA.z, pA.w, pB.x, pB.y, pB.z, pB.w};
            float mfv[16];
#pragma unroll
            for (int q4 = 0; q4 < 4; ++q4)
                *(float4*)&mfv[q4 * 4] = ((const float4*)mrow)[q4];
#pragma unroll
            for (int q = 0; q < 16; ++q) {
                float pf = (q & 1) ? h_hi(pu[q >> 1]) : h_lo(pu[q >> 1]);
                int s = sb + wj + q;
                Ws[wi][wj + q] = (s < nv) ? fminf(pf, mfv[q]) : 0.f;
            }
        }

        {
            const int s = sb + wi;
            const int isrc = s >> 1;
            const float* src = ((s & 1) ? v2 : v1)
                             + ((size_t)isrc * BB + b) * EE + ve;
            float4* dst = (float4*)&Vs[wi][ve];
#pragma unroll
            for (int q = 0; q < 8; ++q) dst[q] = ((const float4*)src)[q];
        }

        __syncthreads();

        for (int k = 0; k < 64; ++k) {
            float wv[4];
#pragma unroll
            for (int i = 0; i < 4; ++i) wv[i] = Ws[r + i][k];
            float vv[8];
            *(float4*)&vv[0] = *(const float4*)&Vs[k][c];
            *(float4*)&vv[4] = *(const float4*)&Vs[k][c + 4];
#pragma unroll
            for (int i = 0; i < 4; ++i)
#pragma unroll
                for (int j = 0; j < 8; ++j)
                    acc[i][j] = fmaf(wv[i], vv[j], acc[i][j]);
        }

        __syncthreads();
    }

#pragma unroll
    for (int i = 0; i < 4; ++i) {
        float* orow = out + ((size_t)(t0 + r + i) * BB + b) * EE + c;
        *(float4*)orow       = make_float4(acc[i][0], acc[i][1], acc[i][2], acc[i][3]);
        *(float4*)(orow + 4) = make_float4(acc[i][4], acc[i][5], acc[i][6], acc[i][7]);
    }
}

// ============================================================
extern "C" void kernel_launch(void* const* d_in, const int* in_sizes, int n_in,
                              void* d_out, int out_size, void* d_ws, size_t ws_size,
                              hipStream_t stream) {
    const float* v1 = (const float*)d_in[0];
    const float* v2 = (const float*)d_in[1];
    const float* d1 = (const float*)d_in[2];
    const float* d2 = (const float*)d_in[3];
    const float* u  = (const float*)d_in[4];
    float* out = (float*)d_out;

    char* ws = (char*)d_ws;
    unsigned short* P = (unsigned short*)ws;                    // 134.2 MB
    float* m   = (float*)(ws + (size_t)BB * TT * SS * 2);       // 2 MB
    float* F   = (float*)(ws + (size_t)BB * TT * SS * 2 + (size_t)TT * SS * 4);
    float* Bvp = F   + (size_t)BB * TT;
    float* d2T = Bvp + (size_t)BB * TT;
    float* FT  = d2T + (size_t)BB * TT;

    prefixF<<<dim3(BB), dim3(64), 0, stream>>>(d1, d2, u, F, Bvp, d2T, FT);
    genP   <<<dim3(BB * 8), dim3(256), 0, stream>>>(F, Bvp, d2T, P);
    calcM  <<<dim3(TT), dim3(256), 0, stream>>>(F, Bvp, FT, u, m);
    phaseC <<<dim3(BB * 8), dim3(256), 0, stream>>>(P, m, v1, v2, out);
}

// Round 4
// 284.227 us; speedup vs baseline: 3.7310x; 1.2898x over previous
//
#include <hip/hip_runtime.h>
#include <cstdint>
#include <cstddef>

#define TT 512
#define BB 128
#define EE 128
#define SS 1024
#define NEG_INF (-1e30f)

typedef _Float16 half8 __attribute__((ext_vector_type(8)));
typedef float floatx4 __attribute__((ext_vector_type(4)));

// ---------- fp16 helpers ----------
__device__ __forceinline__ unsigned int pkh(float x, float y) {
    _Float16 hx = (_Float16)x, hy = (_Float16)y;
    unsigned short bx, by;
    __builtin_memcpy(&bx, &hx, 2); __builtin_memcpy(&by, &hy, 2);
    return (unsigned int)bx | ((unsigned int)by << 16);
}

// ============================================================
// prefixF: per-b prefix sums. F[b][t] = sum_{k<=t}(u-d1-d2),
// Bv[b][t] = F[t-1] - d1[t], d2T[b][t] = d2[t,b], FT[t][b] = F[b][t].
// ============================================================
__global__ __launch_bounds__(64) void prefixF(
    const float* __restrict__ d1, const float* __restrict__ d2,
    const float* __restrict__ u,
    float* __restrict__ F, float* __restrict__ Bv,
    float* __restrict__ d2T, float* __restrict__ FT)
{
    const int b = blockIdx.x;
    const int lane = threadIdx.x;
    const int t0 = lane * 8;

    float l1[8], l2[8], g[8];
#pragma unroll
    for (int j = 0; j < 8; ++j) {
        const int t = t0 + j;
        l1[j] = d1[t * BB + b];
        l2[j] = d2[t * BB + b];
        g[j] = u[t * BB + b] - l1[j] - l2[j];
    }
    float p[8], s = 0.f;
#pragma unroll
    for (int j = 0; j < 8; ++j) { s += g[j]; p[j] = s; }

    float v = s;
#pragma unroll
    for (int off = 1; off < 64; off <<= 1) {
        float o = __shfl_up(v, off);
        if (lane >= off) v += o;
    }
    const float excl = v - s;

    float Fv[8];
#pragma unroll
    for (int j = 0; j < 8; ++j) Fv[j] = excl + p[j];

#pragma unroll
    for (int j = 0; j < 8; ++j) {
        const int t = t0 + j;
        const float Fm1 = (j > 0) ? Fv[j - 1] : excl;
        F [b * TT + t] = Fv[j];
        Bv[b * TT + t] = Fm1 - l1[j];
        d2T[b * TT + t] = l2[j];
        FT[t * BB + b] = Fv[j];
    }
}

// ============================================================
// calcM: m[t,s] = max_b(u - used) via closed form.
// ============================================================
__global__ __launch_bounds__(256) void calcM(
    const float* __restrict__ F, const float* __restrict__ Bvg,
    const float* __restrict__ FT, const float* __restrict__ u,
    float* __restrict__ m)
{
    const int t = blockIdx.x;
    const int tid = threadIdx.x;

    __shared__ float Fs[BB][33];
    __shared__ float Bs[BB][33];
    __shared__ float cand[BB][65];
    __shared__ float red[4][64];
    __shared__ float us[BB];
    __shared__ float Ftb[BB];
    __shared__ float Rc[BB];

    if (tid < BB) {
        us[tid]  = u[t * BB + tid];
        Ftb[tid] = FT[t * BB + tid];
        Rc[tid]  = NEG_INF;
    }

    const int nck = (t >> 5) + 1;
    for (int ck = nck - 1; ck >= 0; --ck) {
        const int ib = ck * 32;
        __syncthreads();
        for (int q = tid; q < BB * 32; q += 256) {
            const int bb = q >> 5, j = q & 31;
            Fs[bb][j] = F  [bb * TT + ib + j];
            Bs[bb][j] = Bvg[bb * TT + ib + j];
        }
        __syncthreads();

        if (tid < BB) {
            const int b = tid;
            float R = Rc[b];
            const float Ft = Ftb[b];
            const int itop = min(t, ib + 31);
            for (int i = itop; i >= ib; --i) {
                const int j = i - ib;
                if (i < t) R = fmaxf(R, Fs[b][j]);
                cand[b][2 * j]     = Ft - fmaxf(Bs[b][j], R);
                cand[b][2 * j + 1] = (i == t) ? us[b] : (Ft - R);
            }
            Rc[b] = R;
        }
        __syncthreads();

        {
            const int s = tid & 63, g = tid >> 6;
            float mx = NEG_INF;
            const int b0 = g * 32;
#pragma unroll 8
            for (int bb = b0; bb < b0 + 32; ++bb) mx = fmaxf(mx, cand[bb][s]);
            red[g][s] = mx;
            __syncthreads();
            if (tid < 64) {
                const float r = fmaxf(fmaxf(red[0][tid], red[1][tid]),
                                      fmaxf(red[2][tid], red[3][tid]));
                const int s_glob = 64 * ck + tid;
                if (s_glob < 2 * t + 2) m[(size_t)t * SS + s_glob] = r;
            }
        }
    }
}

// ============================================================
// phaseC_mfma: out[t,b,:] = sum_s min(a(i,t), m[t,s]) * V[b,s,:]
// W computed on the fly (no P array); fp16 MFMA 16x16x32, fp32 acc.
// Grid 1024 = b(128) x t-tile(8, heavy first), 256 thr = 4 waves.
// LDS (36.6 KB): Ws f16[64][72] | Vt f16[128][72] | Fr/S0/Bv[576] |
//                Lt[7][64] sparse range-max | d2s[64]
// ============================================================
#define WSO 0
#define VTO 2304
#define FRO 6912
#define S0O 7488
#define BVO 8064
#define LTO 8640
#define D2O 9088

__device__ __forceinline__ float tileQ(const float* Lt, int lo, int hi) {
    const int len = hi - lo + 1;                  // >= 1
    const int j = 31 - __builtin_clz(len);
    return fmaxf(Lt[j * 64 + lo], Lt[j * 64 + hi + 1 - (1 << j)]);
}

__global__ __launch_bounds__(256) void phaseC_mfma(
    const float* __restrict__ F, const float* __restrict__ Bvg,
    const float* __restrict__ d2T, const float* __restrict__ m,
    const float* __restrict__ v1, const float* __restrict__ v2,
    float* __restrict__ out)
{
    const int b  = blockIdx.x & (BB - 1);
    const int tt = 7 - (blockIdx.x >> 7);
    const int t0 = tt * 64;
    const int tid = threadIdx.x;

    __shared__ float sh[9152];

    // ---- block init: Fr, Bv, d2s, S0 suffix-max, tile sparse table ----
    const int nF = t0 + 64;
    for (int k = tid; k < nF; k += 256) {
        sh[FRO + k] = F[b * TT + k];
        sh[BVO + k] = Bvg[b * TT + k];
    }
    if (tid < 64) sh[D2O + tid] = d2T[b * TT + t0 + tid];
    __syncthreads();

    // S0[k] = max F over [k, t0-1]   (NEG_INF for k >= t0)
    {
        const int k1 = tid, k2 = tid + 256, k3 = tid + 512;
        sh[S0O + k1] = (k1 < t0) ? sh[FRO + k1] : NEG_INF;
        sh[S0O + k2] = (k2 < t0) ? sh[FRO + k2] : NEG_INF;
        if (k3 < 576) sh[S0O + k3] = NEG_INF;
        if (tid < 64) sh[LTO + tid] = sh[FRO + t0 + tid];   // Lt[0]
        __syncthreads();
        for (int off = 1; off < t0; off <<= 1) {
            float a1 = sh[S0O + k1]; if (k1 + off < 576) a1 = fmaxf(a1, sh[S0O + k1 + off]);
            float a2 = sh[S0O + k2]; if (k2 + off < 576) a2 = fmaxf(a2, sh[S0O + k2 + off]);
            __syncthreads();
            sh[S0O + k1] = a1; sh[S0O + k2] = a2;
            __syncthreads();
        }
        // sparse table levels 1..6 over the 64 tile rows
        for (int j = 1; j < 7; ++j) {
            float v = 0.f;
            if (tid < 64)
                v = fmaxf(sh[LTO + (j - 1) * 64 + tid],
                          sh[LTO + (j - 1) * 64 + min(tid + (1 << (j - 1)), 63)]);
            __syncthreads();
            if (tid < 64) sh[LTO + j * 64 + tid] = v;
            __syncthreads();
        }
    }

    floatx4 acc[8];
#pragma unroll
    for (int j = 0; j < 8; ++j) acc[j] = (floatx4)0.f;

    const int lane = tid & 63, w = tid >> 6;
    const int il = tid & 31, g = tid >> 5;         // W staging
    const int ivl = tid >> 3, eb = tid & 7;        // V staging
    const float* Lt = &sh[LTO];

    const int nchunks = 2 * tt + 2;

    for (int ck = 0; ck < nchunks; ++ck) {
        const int ib = 32 * ck;
        __syncthreads();   // previous compute done before LDS overwrite

        // ---- stage W: closed form + min(m), fp16 pairs ----
        {
            const int i = ib + il;
            const float Ai = (i > 0) ? sh[FRO + i - 1] : 0.f;
            const float Bi = sh[BVO + i];
            const bool below = (i < t0);           // wave-uniform
            const float S0i = below ? sh[S0O + i] : 0.f;
#pragma unroll
            for (int r8 = 0; r8 < 8; ++r8) {
                const int t_l = 8 * g + r8;
                const int t = t0 + t_l;
                float w0 = 0.f, w1 = 0.f;
                if (i <= t) {
                    float R;
                    if (below) {
                        const float qq = (t_l > 0) ? tileQ(Lt, 0, t_l - 1) : NEG_INF;
                        R = fmaxf(S0i, qq);
                    } else {
                        const int li = i - t0;
                        R = (t_l - 1 >= li) ? tileQ(Lt, li, t_l - 1) : NEG_INF;
                    }
                    const float2 mv = *(const float2*)&m[(size_t)t * SS + 2 * i];
                    const float a0 = fmaxf(Ai, R) - fmaxf(Bi, R);
                    const float a1 = (i == t) ? sh[D2O + t_l] : fmaxf(Bi - R, 0.f);
                    w0 = fminf(a0, mv.x);
                    w1 = fminf(a1, mv.y);
                }
                ((unsigned int*)sh)[WSO * 0 + t_l * 36 + il] = pkh(w0, w1);
            }
        }

        // ---- stage V: transpose-on-the-fly, fp16 [e][s] ----
        {
            const int iv = ib + ivl;
            const float* pv1 = v1 + ((size_t)iv * BB + b) * EE;
            const float* pv2 = v2 + ((size_t)iv * BB + b) * EE;
#pragma unroll
            for (int it = 0; it < 4; ++it) {
                const int e0 = 4 * eb + 32 * it;
                const float4 x1 = *(const float4*)&pv1[e0];
                const float4 x2 = *(const float4*)&pv2[e0];
                unsigned int* vt = (unsigned int*)sh + VTO;
                vt[(e0 + 0) * 36 + ivl] = pkh(x1.x, x2.x);
                vt[(e0 + 1) * 36 + ivl] = pkh(x1.y, x2.y);
                vt[(e0 + 2) * 36 + ivl] = pkh(x1.z, x2.z);
                vt[(e0 + 3) * 36 + ivl] = pkh(x1.w, x2.w);
            }
        }

        __syncthreads();

        // ---- MFMA: 2 k-steps x 8 e-tiles ----
        {
            const _Float16* WsH = (const _Float16*)sh;
            const _Float16* VtH = (const _Float16*)(sh + VTO);
            const int arow = 16 * w + (lane & 15);
            const int kq = (lane >> 4) * 8;
#pragma unroll
            for (int k2 = 0; k2 < 64; k2 += 32) {
                const half8 av = *(const half8*)&WsH[arow * 72 + kq + k2];
#pragma unroll
                for (int j = 0; j < 8; ++j) {
                    const half8 bv = *(const half8*)&VtH[(16 * j + (lane & 15)) * 72 + kq + k2];
                    acc[j] = __builtin_amdgcn_mfma_f32_16x16x32_f16(av, bv, acc[j], 0, 0, 0);
                }
            }
        }
    }

    // ---- epilogue: direct dword stores (64B-coalesced per quarter-wave) ----
    {
        const int q = lane >> 4, n = lane & 15;
#pragma unroll
        for (int j = 0; j < 8; ++j) {
#pragma unroll
            for (int reg = 0; reg < 4; ++reg) {
                const int t = t0 + 16 * w + 4 * q + reg;
                out[((size_t)t * BB + b) * EE + 16 * j + n] = acc[j][reg];
            }
        }
    }
}

// ============================================================
extern "C" void kernel_launch(void* const* d_in, const int* in_sizes, int n_in,
                              void* d_out, int out_size, void* d_ws, size_t ws_size,
                              hipStream_t stream) {
    const float* v1 = (const float*)d_in[0];
    const float* v2 = (const float*)d_in[1];
    const float* d1 = (const float*)d_in[2];
    const float* d2 = (const float*)d_in[3];
    const float* u  = (const float*)d_in[4];
    float* out = (float*)d_out;

    char* ws = (char*)d_ws;
    float* m   = (float*)ws;                                   // 2 MB
    float* F   = (float*)(ws + (size_t)TT * SS * 4);
    float* Bvp = F   + (size_t)BB * TT;
    float* d2T = Bvp + (size_t)BB * TT;
    float* FT  = d2T + (size_t)BB * TT;

    prefixF<<<dim3(BB), dim3(64), 0, stream>>>(d1, d2, u, F, Bvp, d2T, FT);
    calcM  <<<dim3(TT), dim3(256), 0, stream>>>(F, Bvp, FT, u, m);
    phaseC_mfma<<<dim3(BB * 8), dim3(256), 0, stream>>>(F, Bvp, d2T, m, v1, v2, out);
}

// Round 5
// 241.186 us; speedup vs baseline: 4.3968x; 1.1785x over previous
//
#include <hip/hip_runtime.h>
#include <cstdint>
#include <cstddef>

#define TT 512
#define BB 128
#define EE 128
#define SS 1024
#define NEG_INF (-1e30f)

typedef _Float16 half8 __attribute__((ext_vector_type(8)));
typedef float floatx4 __attribute__((ext_vector_type(4)));

// ---------- fp16 helpers ----------
__device__ __forceinline__ unsigned int pkh(float x, float y) {
    _Float16 hx = (_Float16)x, hy = (_Float16)y;
    unsigned short bx, by;
    __builtin_memcpy(&bx, &hx, 2); __builtin_memcpy(&by, &hy, 2);
    return (unsigned int)bx | ((unsigned int)by << 16);
}

// ============================================================
// prefixF: per-b prefix sums. F[b][t] = sum_{k<=t}(u-d1-d2),
// Bv[b][t] = F[t-1] - d1[t], d2T[b][t] = d2[t,b], FT[t][b] = F[b][t].
// ============================================================
__global__ __launch_bounds__(64) void prefixF(
    const float* __restrict__ d1, const float* __restrict__ d2,
    const float* __restrict__ u,
    float* __restrict__ F, float* __restrict__ Bv,
    float* __restrict__ d2T, float* __restrict__ FT)
{
    const int b = blockIdx.x;
    const int lane = threadIdx.x;
    const int t0 = lane * 8;

    float l1[8], l2[8], g[8];
#pragma unroll
    for (int j = 0; j < 8; ++j) {
        const int t = t0 + j;
        l1[j] = d1[t * BB + b];
        l2[j] = d2[t * BB + b];
        g[j] = u[t * BB + b] - l1[j] - l2[j];
    }
    float p[8], s = 0.f;
#pragma unroll
    for (int j = 0; j < 8; ++j) { s += g[j]; p[j] = s; }

    float v = s;
#pragma unroll
    for (int off = 1; off < 64; off <<= 1) {
        float o = __shfl_up(v, off);
        if (lane >= off) v += o;
    }
    const float excl = v - s;

    float Fv[8];
#pragma unroll
    for (int j = 0; j < 8; ++j) Fv[j] = excl + p[j];

#pragma unroll
    for (int j = 0; j < 8; ++j) {
        const int t = t0 + j;
        const float Fm1 = (j > 0) ? Fv[j - 1] : excl;
        F [b * TT + t] = Fv[j];
        Bv[b * TT + t] = Fm1 - l1[j];
        d2T[b * TT + t] = l2[j];
        FT[t * BB + b] = Fv[j];
    }
}

// ============================================================
// calcM v2: m[t,s] = max_b(u - used) via closed form.
// 512 blocks (t = 511 - blockIdx, heavy first) x 256 threads.
// Chunks of 32 i (descending). Thread = (b, half-of-16): register
// suffix-max (15-deep chain) + carry ping-pong; all cand values
// computed independently (full ILP); then cross-b max reduction.
// ============================================================
__global__ __launch_bounds__(256) void calcM(
    const float* __restrict__ F, const float* __restrict__ Bvg,
    const float* __restrict__ FT, const float* __restrict__ u,
    float* __restrict__ m)
{
    const int t = (TT - 1) - blockIdx.x;
    const int tid = threadIdx.x;
    const int b = tid & 127;
    const int h = tid >> 7;          // 0 = lower 16 i of chunk, 1 = upper 16
    const int jbase = 16 * h;

    __shared__ float Fs[BB][33];     // stride 33: conflict-free lane-varies-b
    __shared__ float Bs[BB][33];
    __shared__ float cand[BB][66];   // stride 66: 2-way (free)
    __shared__ float Tot[2][BB];
    __shared__ float Rc[2][BB];      // ping-pong carry
    __shared__ float red[4][64];
    __shared__ float us_s[BB];
    __shared__ float Ftb[BB];

    if (tid < BB) {
        us_s[tid] = u[t * BB + tid];
        Ftb[tid]  = FT[t * BB + tid];
        Rc[0][tid] = NEG_INF;
    }

    int rd = 0;
    const int nck = (t >> 5) + 1;
    for (int ck = nck - 1; ck >= 0; --ck) {
        const int ib = ck * 32;

        __syncthreads();   // (a) prev reduce done; Fs/Bs/Tot reusable

        // ---- stage Fs/Bs chunk [ib, ib+32) for all 128 b ----
#pragma unroll
        for (int q = 0; q < 4; ++q) {
            const int idx = tid + 256 * q;
            const int row = idx >> 3;
            const int j4 = (idx & 7) * 4;
            const float4 fv = *(const float4*)&F  [row * TT + ib + j4];
            const float4 bv = *(const float4*)&Bvg[row * TT + ib + j4];
            Fs[row][j4] = fv.x; Fs[row][j4 + 1] = fv.y;
            Fs[row][j4 + 2] = fv.z; Fs[row][j4 + 3] = fv.w;
            Bs[row][j4] = bv.x; Bs[row][j4 + 1] = bv.y;
            Bs[row][j4 + 2] = bv.z; Bs[row][j4 + 3] = bv.w;
        }
        __syncthreads();   // (b) stage visible

        // ---- register suffix-max over my 16 i (masked to i < t) ----
        float v[16], sfx[16];
#pragma unroll
        for (int j = 0; j < 16; ++j) {
            const int i = ib + jbase + j;
            v[j] = (i < t) ? Fs[b][jbase + j] : NEG_INF;
        }
        sfx[15] = v[15];
#pragma unroll
        for (int j = 14; j >= 0; --j) sfx[j] = fmaxf(v[j], sfx[j + 1]);
        Tot[h][b] = sfx[0];
        __syncthreads();   // (c) Tot visible

        float carry = Rc[rd][b];
        if (h == 0) {
            carry = fmaxf(carry, Tot[1][b]);
            Rc[rd ^ 1][b] = fmaxf(carry, sfx[0]);   // carry into next (lower) chunk
        }

        const float Ft = Ftb[b];
#pragma unroll
        for (int j = 0; j < 16; ++j) {
            const int jj = jbase + j;
            const int i = ib + jj;
            const float R = fmaxf(sfx[j], carry);
            const float c0 = Ft - fmaxf(Bs[b][jj], R);
            const float c1 = (i == t) ? us_s[b] : (Ft - R);
            cand[b][2 * jj]     = c0;
            cand[b][2 * jj + 1] = c1;
        }
        __syncthreads();   // (d) cand visible

        // ---- cross-b max for the 64 s-columns of this chunk ----
        {
            const int s = tid & 63, g = tid >> 6;
            float mx = NEG_INF;
            const int b0 = g * 32;
#pragma unroll 8
            for (int bb = b0; bb < b0 + 32; ++bb) mx = fmaxf(mx, cand[bb][s]);
            red[g][s] = mx;
        }
        __syncthreads();   // (e) red visible
        if (tid < 64) {
            const float r = fmaxf(fmaxf(red[0][tid], red[1][tid]),
                                  fmaxf(red[2][tid], red[3][tid]));
            const int s_glob = 2 * ib + tid;
            if (s_glob < 2 * t + 2) m[(size_t)t * SS + s_glob] = r;
        }

        rd ^= 1;
    }
}

// ============================================================
// phaseC_mfma: out[t,b,:] = sum_s min(a(i,t), m[t,s]) * V[b,s,:]
// W computed on the fly (no P array); fp16 MFMA 16x16x32, fp32 acc.
// Grid 1024 = b(128) x t-tile(8, heavy first), 256 thr = 4 waves.
// ============================================================
#define WSO 0
#define VTO 2304
#define FRO 6912
#define S0O 7488
#define BVO 8064
#define LTO 8640
#define D2O 9088

__device__ __forceinline__ float tileQ(const float* Lt, int lo, int hi) {
    const int len = hi - lo + 1;                  // >= 1
    const int j = 31 - __builtin_clz(len);
    return fmaxf(Lt[j * 64 + lo], Lt[j * 64 + hi + 1 - (1 << j)]);
}

__global__ __launch_bounds__(256) void phaseC_mfma(
    const float* __restrict__ F, const float* __restrict__ Bvg,
    const float* __restrict__ d2T, const float* __restrict__ m,
    const float* __restrict__ v1, const float* __restrict__ v2,
    float* __restrict__ out)
{
    const int b  = blockIdx.x & (BB - 1);
    const int tt = 7 - (blockIdx.x >> 7);
    const int t0 = tt * 64;
    const int tid = threadIdx.x;

    __shared__ float sh[9152];

    const int nF = t0 + 64;
    for (int k = tid; k < nF; k += 256) {
        sh[FRO + k] = F[b * TT + k];
        sh[BVO + k] = Bvg[b * TT + k];
    }
    if (tid < 64) sh[D2O + tid] = d2T[b * TT + t0 + tid];
    __syncthreads();

    // S0[k] = max F over [k, t0-1]   (NEG_INF for k >= t0)
    {
        const int k1 = tid, k2 = tid + 256, k3 = tid + 512;
        sh[S0O + k1] = (k1 < t0) ? sh[FRO + k1] : NEG_INF;
        sh[S0O + k2] = (k2 < t0) ? sh[FRO + k2] : NEG_INF;
        if (k3 < 576) sh[S0O + k3] = NEG_INF;
        if (tid < 64) sh[LTO + tid] = sh[FRO + t0 + tid];   // Lt[0]
        __syncthreads();
        for (int off = 1; off < t0; off <<= 1) {
            float a1 = sh[S0O + k1]; if (k1 + off < 576) a1 = fmaxf(a1, sh[S0O + k1 + off]);
            float a2 = sh[S0O + k2]; if (k2 + off < 576) a2 = fmaxf(a2, sh[S0O + k2 + off]);
            __syncthreads();
            sh[S0O + k1] = a1; sh[S0O + k2] = a2;
            __syncthreads();
        }
        for (int j = 1; j < 7; ++j) {
            float v = 0.f;
            if (tid < 64)
                v = fmaxf(sh[LTO + (j - 1) * 64 + tid],
                          sh[LTO + (j - 1) * 64 + min(tid + (1 << (j - 1)), 63)]);
            __syncthreads();
            if (tid < 64) sh[LTO + j * 64 + tid] = v;
            __syncthreads();
        }
    }

    floatx4 acc[8];
#pragma unroll
    for (int j = 0; j < 8; ++j) acc[j] = (floatx4)0.f;

    const int lane = tid & 63, w = tid >> 6;
    const int il = tid & 31, g = tid >> 5;
    const int ivl = tid >> 3, eb = tid & 7;
    const float* Lt = &sh[LTO];

    const int nchunks = 2 * tt + 2;

    for (int ck = 0; ck < nchunks; ++ck) {
        const int ib = 32 * ck;
        __syncthreads();

        // ---- stage W: closed form + min(m), fp16 pairs ----
        {
            const int i = ib + il;
            const float Ai = (i > 0) ? sh[FRO + i - 1] : 0.f;
            const float Bi = sh[BVO + i];
            const bool below = (i < t0);
            const float S0i = below ? sh[S0O + i] : 0.f;
#pragma unroll
            for (int r8 = 0; r8 < 8; ++r8) {
                const int t_l = 8 * g + r8;
                const int t = t0 + t_l;
                float w0 = 0.f, w1 = 0.f;
                if (i <= t) {
                    float R;
                    if (below) {
                        const float qq = (t_l > 0) ? tileQ(Lt, 0, t_l - 1) : NEG_INF;
                        R = fmaxf(S0i, qq);
                    } else {
                        const int li = i - t0;
                        R = (t_l - 1 >= li) ? tileQ(Lt, li, t_l - 1) : NEG_INF;
                    }
                    const float2 mv = *(const float2*)&m[(size_t)t * SS + 2 * i];
                    const float a0 = fmaxf(Ai, R) - fmaxf(Bi, R);
                    const float a1 = (i == t) ? sh[D2O + t_l] : fmaxf(Bi - R, 0.f);
                    w0 = fminf(a0, mv.x);
                    w1 = fminf(a1, mv.y);
                }
                ((unsigned int*)sh)[WSO * 0 + t_l * 36 + il] = pkh(w0, w1);
            }
        }

        // ---- stage V: transpose-on-the-fly, fp16 [e][s] ----
        {
            const int iv = ib + ivl;
            const float* pv1 = v1 + ((size_t)iv * BB + b) * EE;
            const float* pv2 = v2 + ((size_t)iv * BB + b) * EE;
#pragma unroll
            for (int it = 0; it < 4; ++it) {
                const int e0 = 4 * eb + 32 * it;
                const float4 x1 = *(const float4*)&pv1[e0];
                const float4 x2 = *(const float4*)&pv2[e0];
                unsigned int* vt = (unsigned int*)sh + VTO;
                vt[(e0 + 0) * 36 + ivl] = pkh(x1.x, x2.x);
                vt[(e0 + 1) * 36 + ivl] = pkh(x1.y, x2.y);
                vt[(e0 + 2) * 36 + ivl] = pkh(x1.z, x2.z);
                vt[(e0 + 3) * 36 + ivl] = pkh(x1.w, x2.w);
            }
        }

        __syncthreads();

        // ---- MFMA: 2 k-steps x 8 e-tiles ----
        {
            const _Float16* WsH = (const _Float16*)sh;
            const _Float16* VtH = (const _Float16*)(sh + VTO);
            const int arow = 16 * w + (lane & 15);
            const int kq = (lane >> 4) * 8;
#pragma unroll
            for (int k2 = 0; k2 < 64; k2 += 32) {
                const half8 av = *(const half8*)&WsH[arow * 72 + kq + k2];
#pragma unroll
                for (int j = 0; j < 8; ++j) {
                    const half8 bv = *(const half8*)&VtH[(16 * j + (lane & 15)) * 72 + kq + k2];
                    acc[j] = __builtin_amdgcn_mfma_f32_16x16x32_f16(av, bv, acc[j], 0, 0, 0);
                }
            }
        }
    }

    // ---- epilogue ----
    {
        const int q = lane >> 4, n = lane & 15;
#pragma unroll
        for (int j = 0; j < 8; ++j) {
#pragma unroll
            for (int reg = 0; reg < 4; ++reg) {
                const int t = t0 + 16 * w + 4 * q + reg;
                out[((size_t)t * BB + b) * EE + 16 * j + n] = acc[j][reg];
            }
        }
    }
}

// ============================================================
extern "C" void kernel_launch(void* const* d_in, const int* in_sizes, int n_in,
                              void* d_out, int out_size, void* d_ws, size_t ws_size,
                              hipStream_t stream) {
    const float* v1 = (const float*)d_in[0];
    const float* v2 = (const float*)d_in[1];
    const float* d1 = (const float*)d_in[2];
    const float* d2 = (const float*)d_in[3];
    const float* u  = (const float*)d_in[4];
    float* out = (float*)d_out;

    char* ws = (char*)d_ws;
    float* m   = (float*)ws;                                   // 2 MB
    float* F   = (float*)(ws + (size_t)TT * SS * 4);
    float* Bvp = F   + (size_t)BB * TT;
    float* d2T = Bvp + (size_t)BB * TT;
    float* FT  = d2T + (size_t)BB * TT;

    prefixF<<<dim3(BB), dim3(64), 0, stream>>>(d1, d2, u, F, Bvp, d2T, FT);
    calcM  <<<dim3(TT), dim3(256), 0, stream>>>(F, Bvp, FT, u, m);
    phaseC_mfma<<<dim3(BB * 8), dim3(256), 0, stream>>>(F, Bvp, d2T, m, v1, v2, out);
}

// Round 6
// 211.365 us; speedup vs baseline: 5.0171x; 1.1411x over previous
//
#include <hip/hip_runtime.h>
#include <cstdint>
#include <cstddef>

#define TT 512
#define BB 128
#define EE 128
#define SS 1024
#define NEG_INF (-1e30f)

typedef _Float16 half8 __attribute__((ext_vector_type(8)));
typedef float floatx4 __attribute__((ext_vector_type(4)));

// ---------- fp16 helpers ----------
__device__ __forceinline__ unsigned int pkh(float x, float y) {
    _Float16 hx = (_Float16)x, hy = (_Float16)y;
    unsigned short bx, by;
    __builtin_memcpy(&bx, &hx, 2); __builtin_memcpy(&by, &hy, 2);
    return (unsigned int)bx | ((unsigned int)by << 16);
}

// ============================================================
// prefixF: per-b prefix sums + range-max precompute.
// F[b][t] = sum_{k<=t}(u-d1-d2); Bv[b][t] = F[t-1]-d1[t].
// Also: FT/BvT/CST/HT [t][b] transposed, CMT[c][b]:
//   CS[i] = max(F[i .. chunkEnd(i)])   (inclusive suffix, 32-chunk)
//   H[t]  = max(F[chunkStart(t) .. t-1])  (exclusive prefix; -inf if empty)
//   CM[c] = max over chunk c
// ============================================================
__global__ __launch_bounds__(64) void prefixF(
    const float* __restrict__ d1, const float* __restrict__ d2,
    const float* __restrict__ u,
    float* __restrict__ F, float* __restrict__ Bv,
    float* __restrict__ d2T, float* __restrict__ FT,
    float* __restrict__ BvT, float* __restrict__ CST,
    float* __restrict__ CMT, float* __restrict__ HT)
{
    const int b = blockIdx.x;
    const int lane = threadIdx.x;
    const int t0 = lane * 8;

    float l1[8], l2[8], g[8];
#pragma unroll
    for (int j = 0; j < 8; ++j) {
        const int t = t0 + j;
        l1[j] = d1[t * BB + b];
        l2[j] = d2[t * BB + b];
        g[j] = u[t * BB + b] - l1[j] - l2[j];
    }
    float p[8], s = 0.f;
#pragma unroll
    for (int j = 0; j < 8; ++j) { s += g[j]; p[j] = s; }

    float v = s;
#pragma unroll
    for (int off = 1; off < 64; off <<= 1) {
        float o = __shfl_up(v, off);
        if (lane >= off) v += o;
    }
    const float excl = v - s;

    float Fv[8];
#pragma unroll
    for (int j = 0; j < 8; ++j) Fv[j] = excl + p[j];

#pragma unroll
    for (int j = 0; j < 8; ++j) {
        const int t = t0 + j;
        const float Fm1 = (j > 0) ? Fv[j - 1] : excl;
        const float Bvv = Fm1 - l1[j];
        F  [b * TT + t] = Fv[j];
        Bv [b * TT + t] = Bvv;
        d2T[b * TT + t] = l2[j];
        FT [t * BB + b] = Fv[j];
        BvT[t * BB + b] = Bvv;
    }

    // ---- range-max structures (chunk = 32 t = 4 lanes) ----
    float pm[8], sm[8];
    pm[0] = Fv[0];
#pragma unroll
    for (int j = 1; j < 8; ++j) pm[j] = fmaxf(pm[j - 1], Fv[j]);
    sm[7] = Fv[7];
#pragma unroll
    for (int j = 6; j >= 0; --j) sm[j] = fmaxf(sm[j + 1], Fv[j]);

    float pcar = NEG_INF, scar = NEG_INF;
#pragma unroll
    for (int off = 1; off <= 3; ++off) {
        float xu = __shfl_up(pm[7], off);
        if ((lane & 3) >= off) pcar = fmaxf(pcar, xu);
        float xd = __shfl_down(sm[0], off);
        if ((lane & 3) + off <= 3) scar = fmaxf(scar, xd);
    }

#pragma unroll
    for (int j = 0; j < 8; ++j) {
        const int t = t0 + j;
        const float Hv  = fmaxf(pcar, (j > 0) ? pm[j - 1] : NEG_INF);
        const float CSv = fmaxf(sm[j], scar);
        HT [t * BB + b] = Hv;
        CST[t * BB + b] = CSv;
    }
    if ((lane & 3) == 0)
        CMT[(lane >> 2) * BB + b] = fmaxf(sm[0], scar);
}

// ============================================================
// calcM2: m[t, 64*ci + 0..63] fully parallel over (t, chunk ci).
// Off-diag (ci < t>>5): R(i,t) = max(CS[i], CM[ci+1..ct-1], H[t]).
// Diag (ci == t>>5): local masked register suffix-max (exact same
// fmax compositions -> bit-identical to the sequential recurrence).
// Grid dim3(16, 512); blocks with ci > t>>5 exit immediately.
// ============================================================
__global__ __launch_bounds__(256) void calcM2(
    const float* __restrict__ FT, const float* __restrict__ BvT,
    const float* __restrict__ CST, const float* __restrict__ CMT,
    const float* __restrict__ HT, const float* __restrict__ u,
    float* __restrict__ m)
{
    const int t = (int)blockIdx.y;
    const int ci = (int)blockIdx.x;
    const int ct = t >> 5;
    if (ci > ct) return;

    const int tid = threadIdx.x;
    const int b = tid & 127, h = tid >> 7;
    const int ib = 32 * ci;

    __shared__ float cand[BB][66];
    __shared__ float Tot[2][BB];
    __shared__ float red[4][64];

    const float Ft = FT[t * BB + b];

    if (ci < ct) {
        float K = HT[t * BB + b];
        for (int c = ci + 1; c < ct; ++c) K = fmaxf(K, CMT[c * BB + b]);
#pragma unroll
        for (int j = 0; j < 16; ++j) {
            const int jj = 16 * h + j;
            const int i = ib + jj;
            const float R = fmaxf(CST[i * BB + b], K);
            const float Bvv = BvT[i * BB + b];
            cand[b][2 * jj]     = Ft - fmaxf(Bvv, R);
            cand[b][2 * jj + 1] = Ft - R;
        }
    } else {
        float vv[16], sfx[16];
#pragma unroll
        for (int j = 0; j < 16; ++j) {
            const int i = ib + 16 * h + j;
            vv[j] = (i < t) ? FT[i * BB + b] : NEG_INF;
        }
        sfx[15] = vv[15];
#pragma unroll
        for (int j = 14; j >= 0; --j) sfx[j] = fmaxf(vv[j], sfx[j + 1]);
        Tot[h][b] = sfx[0];
        __syncthreads();
        const float carry = (h == 0) ? Tot[1][b] : NEG_INF;
        const float ub = u[t * BB + b];
#pragma unroll
        for (int j = 0; j < 16; ++j) {
            const int jj = 16 * h + j;
            const int i = ib + jj;
            const float R = fmaxf(sfx[j], carry);
            const float Bvv = BvT[i * BB + b];
            cand[b][2 * jj]     = Ft - fmaxf(Bvv, R);
            cand[b][2 * jj + 1] = (i == t) ? ub : (Ft - R);
        }
    }
    __syncthreads();

    {
        const int s = tid & 63, g = tid >> 6;
        float mx = NEG_INF;
        const int b0 = g * 32;
#pragma unroll 8
        for (int bb = b0; bb < b0 + 32; ++bb) mx = fmaxf(mx, cand[bb][s]);
        red[g][s] = mx;
    }
    __syncthreads();
    if (tid < 64) {
        const float r = fmaxf(fmaxf(red[0][tid], red[1][tid]),
                              fmaxf(red[2][tid], red[3][tid]));
        const int s_glob = 64 * ci + tid;
        if (s_glob < 2 * t + 2) m[(size_t)t * SS + s_glob] = r;
    }
}

// ============================================================
// phaseC_mfma: out[t,b,:] = sum_s min(a(i,t), m[t,s]) * V[b,s,:]
// fp16 MFMA 16x16x32, 2x2 wave tiling (wave = 32t x 64e).
// Vt staged via conflict-free ds_write_b64 (thread = e-quad x i-pair).
// Grid 1024 = b(128) x t-tile(8, heavy first), 256 thr = 4 waves.
// ============================================================
#define WSO 0
#define VTO 2304
#define FRO 6912
#define S0O 7488
#define BVO 8064
#define LTO 8640
#define D2O 9088

__device__ __forceinline__ float tileQ(const float* Lt, int lo, int hi) {
    const int len = hi - lo + 1;                  // >= 1
    const int j = 31 - __builtin_clz(len);
    return fmaxf(Lt[j * 64 + lo], Lt[j * 64 + hi + 1 - (1 << j)]);
}

__global__ __launch_bounds__(256) void phaseC_mfma(
    const float* __restrict__ F, const float* __restrict__ Bvg,
    const float* __restrict__ d2T, const float* __restrict__ m,
    const float* __restrict__ v1, const float* __restrict__ v2,
    float* __restrict__ out)
{
    const int b  = blockIdx.x & (BB - 1);
    const int tt = 7 - (blockIdx.x >> 7);
    const int t0 = tt * 64;
    const int tid = threadIdx.x;

    __shared__ float sh[9152];

    const int nF = t0 + 64;
    for (int k = tid; k < nF; k += 256) {
        sh[FRO + k] = F[b * TT + k];
        sh[BVO + k] = Bvg[b * TT + k];
    }
    if (tid < 64) sh[D2O + tid] = d2T[b * TT + t0 + tid];
    __syncthreads();

    // S0[k] = max F over [k, t0-1]   (NEG_INF for k >= t0)
    {
        const int k1 = tid, k2 = tid + 256, k3 = tid + 512;
        sh[S0O + k1] = (k1 < t0) ? sh[FRO + k1] : NEG_INF;
        sh[S0O + k2] = (k2 < t0) ? sh[FRO + k2] : NEG_INF;
        if (k3 < 576) sh[S0O + k3] = NEG_INF;
        if (tid < 64) sh[LTO + tid] = sh[FRO + t0 + tid];   // Lt[0]
        __syncthreads();
        for (int off = 1; off < t0; off <<= 1) {
            float a1 = sh[S0O + k1]; if (k1 + off < 576) a1 = fmaxf(a1, sh[S0O + k1 + off]);
            float a2 = sh[S0O + k2]; if (k2 + off < 576) a2 = fmaxf(a2, sh[S0O + k2 + off]);
            __syncthreads();
            sh[S0O + k1] = a1; sh[S0O + k2] = a2;
            __syncthreads();
        }
        for (int j = 1; j < 7; ++j) {
            float v = 0.f;
            if (tid < 64)
                v = fmaxf(sh[LTO + (j - 1) * 64 + tid],
                          sh[LTO + (j - 1) * 64 + min(tid + (1 << (j - 1)), 63)]);
            __syncthreads();
            if (tid < 64) sh[LTO + j * 64 + tid] = v;
            __syncthreads();
        }
    }

    floatx4 acc[2][4];
#pragma unroll
    for (int r = 0; r < 2; ++r)
#pragma unroll
        for (int j = 0; j < 4; ++j) acc[r][j] = (floatx4)0.f;

    const int lane = tid & 63, w = tid >> 6;
    const int wr = w >> 1, wc = w & 1;            // 2x2 wave grid
    const int n = lane & 15;
    const int kq = (lane >> 4) * 8;
    const int il = tid & 31, g = tid >> 5;        // W staging
    const int veb = tid & 7;                      // V staging: e quad
    const int vip = ((tid >> 3) & 7) + 8 * wc;    // i-pair 0..15
    const int veh = wr * 64;                      // e half
    const float* Lt = &sh[LTO];

    const int nchunks = 2 * tt + 2;

    for (int ck = 0; ck < nchunks; ++ck) {
        const int ib = 32 * ck;
        __syncthreads();

        // ---- stage W: closed form + min(m), fp16 pairs ----
        {
            const int i = ib + il;
            const float Ai = (i > 0) ? sh[FRO + i - 1] : 0.f;
            const float Bi = sh[BVO + i];
            const bool below = (i < t0);
            const float S0i = below ? sh[S0O + i] : 0.f;
#pragma unroll
            for (int r8 = 0; r8 < 8; ++r8) {
                const int t_l = 8 * g + r8;
                const int t = t0 + t_l;
                float w0 = 0.f, w1 = 0.f;
                if (i <= t) {
                    float R;
                    if (below) {
                        const float qq = (t_l > 0) ? tileQ(Lt, 0, t_l - 1) : NEG_INF;
                        R = fmaxf(S0i, qq);
                    } else {
                        const int li = i - t0;
                        R = (t_l - 1 >= li) ? tileQ(Lt, li, t_l - 1) : NEG_INF;
                    }
                    const float2 mv = *(const float2*)&m[(size_t)t * SS + 2 * i];
                    const float a0 = fmaxf(Ai, R) - fmaxf(Bi, R);
                    const float a1 = (i == t) ? sh[D2O + t_l] : fmaxf(Bi - R, 0.f);
                    w0 = fminf(a0, mv.x);
                    w1 = fminf(a1, mv.y);
                }
                ((unsigned int*)sh)[t_l * 36 + il] = pkh(w0, w1);
            }
        }

        // ---- stage V: conflict-free b64 writes, fp16 [e][s] ----
        {
            const int i0 = ib + 2 * vip, i1 = i0 + 1;
            const float* p10 = v1 + ((size_t)i0 * BB + b) * EE;
            const float* p11 = v1 + ((size_t)i1 * BB + b) * EE;
            const float* p20 = v2 + ((size_t)i0 * BB + b) * EE;
            const float* p21 = v2 + ((size_t)i1 * BB + b) * EE;
            unsigned int* vt = (unsigned int*)sh + VTO;
            const int dw = 2 * vip;
#pragma unroll
            for (int c = 0; c < 2; ++c) {
                const int e0 = 4 * veb + 32 * c + veh;
                const float4 xa = *(const float4*)&p10[e0];
                const float4 xb = *(const float4*)&p11[e0];
                const float4 ya = *(const float4*)&p20[e0];
                const float4 yb = *(const float4*)&p21[e0];
                uint2 s0 = make_uint2(pkh(xa.x, ya.x), pkh(xb.x, yb.x));
                *(uint2*)&vt[(e0 + 0) * 36 + dw] = s0;
                uint2 s1 = make_uint2(pkh(xa.y, ya.y), pkh(xb.y, yb.y));
                *(uint2*)&vt[(e0 + 1) * 36 + dw] = s1;
                uint2 s2 = make_uint2(pkh(xa.z, ya.z), pkh(xb.z, yb.z));
                *(uint2*)&vt[(e0 + 2) * 36 + dw] = s2;
                uint2 s3 = make_uint2(pkh(xa.w, ya.w), pkh(xb.w, yb.w));
                *(uint2*)&vt[(e0 + 3) * 36 + dw] = s3;
            }
        }

        __syncthreads();

        // ---- MFMA: 2 k-steps x (2 t-rows x 4 e-tiles) per wave ----
        {
            const _Float16* WsH = (const _Float16*)sh;
            const _Float16* VtH = (const _Float16*)(sh + VTO);
#pragma unroll
            for (int k2 = 0; k2 < 64; k2 += 32) {
                const half8 av0 = *(const half8*)&WsH[(32 * wr + n) * 72 + kq + k2];
                const half8 av1 = *(const half8*)&WsH[(32 * wr + 16 + n) * 72 + kq + k2];
#pragma unroll
                for (int j = 0; j < 4; ++j) {
                    const half8 bv = *(const half8*)&VtH[(64 * wc + 16 * j + n) * 72 + kq + k2];
                    acc[0][j] = __builtin_amdgcn_mfma_f32_16x16x32_f16(av0, bv, acc[0][j], 0, 0, 0);
                    acc[1][j] = __builtin_amdgcn_mfma_f32_16x16x32_f16(av1, bv, acc[1][j], 0, 0, 0);
                }
            }
        }
    }

    // ---- epilogue ----
    {
        const int q = lane >> 4;
#pragma unroll
        for (int r = 0; r < 2; ++r) {
#pragma unroll
            for (int j = 0; j < 4; ++j) {
#pragma unroll
                for (int reg = 0; reg < 4; ++reg) {
                    const int t = t0 + 32 * wr + 16 * r + 4 * q + reg;
                    const int col = 64 * wc + 16 * j + n;
                    out[((size_t)t * BB + b) * EE + col] = acc[r][j][reg];
                }
            }
        }
    }
}

// ============================================================
extern "C" void kernel_launch(void* const* d_in, const int* in_sizes, int n_in,
                              void* d_out, int out_size, void* d_ws, size_t ws_size,
                              hipStream_t stream) {
    const float* v1 = (const float*)d_in[0];
    const float* v2 = (const float*)d_in[1];
    const float* d1 = (const float*)d_in[2];
    const float* d2 = (const float*)d_in[3];
    const float* u  = (const float*)d_in[4];
    float* out = (float*)d_out;

    char* ws = (char*)d_ws;
    float* m   = (float*)ws;                                   // 2 MB
    float* F   = m   + (size_t)TT * SS;
    float* Bvp = F   + (size_t)BB * TT;
    float* d2T = Bvp + (size_t)BB * TT;
    float* FT  = d2T + (size_t)BB * TT;
    float* BvT = FT  + (size_t)BB * TT;
    float* CST = BvT + (size_t)BB * TT;
    float* HT  = CST + (size_t)BB * TT;
    float* CMT = HT  + (size_t)BB * TT;                        // 16*128

    prefixF<<<dim3(BB), dim3(64), 0, stream>>>(d1, d2, u, F, Bvp, d2T, FT,
                                               BvT, CST, CMT, HT);
    calcM2 <<<dim3(16, TT), dim3(256), 0, stream>>>(FT, BvT, CST, CMT, HT, u, m);
    phaseC_mfma<<<dim3(BB * 8), dim3(256), 0, stream>>>(F, Bvp, d2T, m, v1, v2, out);
}